// Round 20
// baseline (1473.060 us; speedup 1.0000x reference)
//
#include <hip/hip_runtime.h>

typedef float f32x4 __attribute__((ext_vector_type(4)));
typedef _Float16 half8 __attribute__((ext_vector_type(8)));

constexpr int kC  = 1024;
constexpr int kFF = 4096;
constexpr size_t MB1 = 1ull << 20;
constexpr long long CB = 8388608ll;   // 8192*1024

// ---------------- workspace layout (bytes) ----------------
constexpr size_t O_W1H = 0;          // QKV^T hi [3072][1024] half (x64)
constexpr size_t O_W1L = 6*MB1;      // QKV^T lo
constexpr size_t O_WOH = 12*MB1;     // Wo^T hi
constexpr size_t O_WOL = 14*MB1;     // Wo^T lo
constexpr size_t O_WBT = 16*MB1;     // WbT [4096][2048] half (rows k>=1024 prescaled 1/16)
constexpr size_t O_WKF = 32*MB1;     // 6 x [4096][1024] half
constexpr size_t O_WVF = 80*MB1;     // 6 x [1024][4096] half
constexpr size_t O_WQT = 128*MB1;    // 2 x [1024][1024] half each
constexpr size_t O_WKT = 132*MB1;
constexpr size_t O_WVT = 136*MB1;
constexpr size_t O_WOT = 140*MB1;
constexpr size_t O_XH  = 144*MB1;    // xlnHi; later stbuf; later kkpool [144,272); later pfx_e [144,208)
constexpr size_t O_XL  = 160*MB1;    // xlnLo
constexpr size_t O_RKV = 176*MB1;    // rkv f32 [8192][3072]; later hF; kk tail; kp/vp [208,272)
constexpr size_t O_RWH = 272*MB1;    // rwkvHi (x16) half (LIVE through transformer experts in bigws path)
constexpr size_t O_RWL = 288*MB1;    // rwkvLo half; later hH
constexpr size_t O_AW  = 304*MB1;    // attw f32 [8192][64]
constexpr size_t O_CNT = 306*MB1;
constexpr size_t O_OFF = O_CNT + 256;
constexpr size_t O_LTOK = O_CNT + 1024;
constexpr size_t O_LW   = O_LTOK + 8ull*8192*sizeof(int);
constexpr size_t O_INV  = O_LW + 8ull*8192*sizeof(float);
constexpr size_t WS_NEED = O_INV + 2ull*8192*sizeof(int) + 1024;
// optional no-atomic FFN2 stage (guarded by ws_size); reused for q/o after combine
constexpr size_t O_STAGE = 308*MB1;  // [16384][1024] half = 32MB (per K-half slab)
constexpr size_t WS_BIG  = 340*MB1;
constexpr size_t WS_SPLIT= 373*MB1;  // stage2 slab [340,372) + slack
constexpr size_t STAGE_SLAB = 16777216; // halfs per slab (32MB)

__device__ __forceinline__ void gload16(const _Float16* g, _Float16* l){
  __builtin_amdgcn_global_load_lds(
      (const __attribute__((address_space(1))) void*)g,
      (__attribute__((address_space(3))) void*)l, 16, 0, 0);
}

// bijective XCD-aware block swizzle (m204): contiguous chunk per XCD
__device__ __forceinline__ int xcd_swz(int bid, int nwg){
  int q = nwg >> 3, r = nwg & 7;
  int x = bid & 7, i = bid >> 3;
  return (x < r ? x*(q+1) : r*(q+1) + (x-r)*q) + i;
}

// dmode 0: supertiled (dense); dmode 1: mb-fast.
__device__ __forceinline__ void decode_mb_nb(int bid, int nNB, int nMB, int dmode,
                                             int& mb, int& nb){
  if (dmode == 0){
    int m8 = bid & 7;
    int t = bid >> 3;
    nb = t % nNB;
    mb = m8 * (nMB >> 3) + t / nNB;
  } else {
    mb = bid % nMB;
    nb = bid / nMB;
  }
}

// ---------------- small kernels ----------------
__global__ void zero_cnt(int* c){ if (threadIdx.x < 8) c[threadIdx.x] = 0; }

__global__ void calc_off(const int* __restrict__ cnt, int* __restrict__ off){
  if (threadIdx.x == 0){
    int s = 0;
    for (int e = 0; e < 6; ++e){ off[e] = s; s += cnt[e]; }
  }
}

// out[c][r] = in[r][c] * (r<splitR ? sc1 : sc2), half (optional hi/lo split)
__global__ __launch_bounds__(256) void transpose_cvt(
    const float* __restrict__ in, _Float16* __restrict__ outHi,
    _Float16* __restrict__ outLo, int R, int C, float sc1, float sc2,
    int splitR, int split)
{
  __shared__ float tile[32][33];
  size_t zoff = (size_t)blockIdx.z * R * C;
  const float* ip = in + zoff;
  _Float16* oh = outHi + zoff;
  _Float16* ol = outLo ? outLo + zoff : nullptr;
  int c0 = blockIdx.x*32, r0 = blockIdx.y*32;
  int tx = threadIdx.x & 31, ty = threadIdx.x >> 5;
  #pragma unroll
  for (int j = 0; j < 32; j += 8){
    int r = r0+ty+j;
    float s = (r < splitR) ? sc1 : sc2;
    tile[ty+j][tx] = ip[(size_t)r*C + c0+tx] * s;
  }
  __syncthreads();
  #pragma unroll
  for (int j = 0; j < 32; j += 8){
    float v = tile[tx][ty+j];
    _Float16 hi = (_Float16)v;
    oh[(size_t)(c0+ty+j)*R + r0+tx] = hi;
    if (split) ol[(size_t)(c0+ty+j)*R + r0+tx] = (_Float16)(v - (float)hi);
  }
}

// LayerNorm rows of 1024.
__global__ __launch_bounds__(256) void ln_kernel(
    const float* __restrict__ x, const float* __restrict__ g,
    const float* __restrict__ b, float* __restrict__ yF,
    _Float16* __restrict__ yH, _Float16* __restrict__ yHi,
    _Float16* __restrict__ yLo, float fscale)
{
  int row = blockIdx.x, tid = threadIdx.x;
  int lane = tid & 63, wid = tid >> 6;
  __shared__ float red[2][4];
  f32x4 v = ((const f32x4*)(x + (size_t)row*kC))[tid];
  float s = v[0]+v[1]+v[2]+v[3];
  #pragma unroll
  for (int off=32; off; off>>=1) s += __shfl_xor(s, off);
  if (lane==0) red[0][wid] = s;
  __syncthreads();
  float mean = (red[0][0]+red[0][1]+red[0][2]+red[0][3]) * (1.f/1024.f);
  float d0=v[0]-mean, d1=v[1]-mean, d2=v[2]-mean, d3=v[3]-mean;
  float s2 = d0*d0+d1*d1+d2*d2+d3*d3;
  #pragma unroll
  for (int off=32; off; off>>=1) s2 += __shfl_xor(s2, off);
  if (lane==0) red[1][wid] = s2;
  __syncthreads();
  float var = (red[1][0]+red[1][1]+red[1][2]+red[1][3]) * (1.f/1024.f);
  float rs = 1.f / sqrtf(var + 1e-5f);
  f32x4 gg = ((const f32x4*)g)[tid];
  f32x4 bb = ((const f32x4*)b)[tid];
  float y[4];
  y[0] = d0*rs*gg[0]+bb[0];
  y[1] = d1*rs*gg[1]+bb[1];
  y[2] = d2*rs*gg[2]+bb[2];
  y[3] = d3*rs*gg[3]+bb[3];
  size_t base = (size_t)row*kC + tid*4;
  if (yF){
    f32x4 o = {y[0],y[1],y[2],y[3]};
    *(f32x4*)(yF + base) = o;
  }
  if (yH){
    #pragma unroll
    for (int j=0;j<4;j++) yH[base+j] = (_Float16)y[j];
  }
  if (yHi){
    #pragma unroll
    for (int j=0;j<4;j++){
      float ys = y[j]*fscale;
      _Float16 hi = (_Float16)ys;
      yHi[base+j] = hi;
      yLo[base+j] = (_Float16)(ys - (float)hi);
    }
  }
}

// ---------------- fp16-pair emulated "f32" GEMM, 2-phase pipeline, BK=32 ----------
template<int ADDX>
__global__ __launch_bounds__(256) void gemm_emu(
    const _Float16* __restrict__ Ah, const _Float16* __restrict__ Al,
    const _Float16* __restrict__ Bh, const _Float16* __restrict__ Bl,
    float* __restrict__ out, const float* __restrict__ addsrc,
    float* __restrict__ vsplit, int M, int N, int K)
{
  __shared__ _Float16 lAh[2][4096], lAl[2][4096], lBh[2][4096], lBl[2][4096];
  int bid = xcd_swz((int)blockIdx.x, (int)gridDim.x);
  int mb, nb;
  decode_mb_nb(bid, N >> 7, M >> 7, 0, mb, nb);
  int tid = threadIdx.x;
  int lane = tid & 63, wid = tid >> 6;
  int wr = wid >> 1, wc = wid & 1;
  int fr = lane & 15, fg = lane >> 4;
  f32x4 z = {0.f,0.f,0.f,0.f};
  f32x4 acc[4][4];
  #pragma unroll
  for (int m=0;m<4;m++)
    #pragma unroll
    for (int n=0;n<4;n++) acc[m][n] = z;

  size_t arow = (size_t)(mb<<7), brow = (size_t)(nb<<7);
  size_t aoff_s[2], boff_s[2]; int ldst_s[2];
  #pragma unroll
  for (int it=0; it<2; ++it){
    int q = (it<<8) + tid;
    int row = q >> 2, c = q & 3;
    int cg = c ^ ((row >> 1) & 3);       // pre-swizzled source chunk
    aoff_s[it] = (arow+row)*K + (cg<<3);
    boff_s[it] = (brow+row)*K + (cg<<3);
    ldst_s[it] = q<<3;
  }
  auto STAGE = [&](int buf, int kt){
    #pragma unroll
    for (int it=0; it<2; ++it){
      gload16(Ah + aoff_s[it] + kt, &lAh[buf][ldst_s[it]]);
      gload16(Al + aoff_s[it] + kt, &lAl[buf][ldst_s[it]]);
      gload16(Bh + boff_s[it] + kt, &lBh[buf][ldst_s[it]]);
      gload16(Bl + boff_s[it] + kt, &lBl[buf][ldst_s[it]]);
    }
  };

  STAGE(0, 0);
  __syncthreads();
  int nk = K >> 5, cur = 0;
  for (int ki=0; ki<nk; ++ki){
    if (ki+1 < nk) STAGE(cur^1, (ki+1)<<5);
    half8 ah[4], al[4], bh[4], bl[4];
    #pragma unroll
    for (int m=0;m<4;m++){
      int r = (wr<<6)+(m<<4)+fr;
      int off = (r<<5) + ((fg ^ ((r>>1)&3))<<3);
      ah[m] = *(const half8*)&lAh[cur][off];
      al[m] = *(const half8*)&lAl[cur][off];
    }
    #pragma unroll
    for (int n=0;n<4;n++){
      int r = (wc<<6)+(n<<4)+fr;
      int off = (r<<5) + ((fg ^ ((r>>1)&3))<<3);
      bh[n] = *(const half8*)&lBh[cur][off];
      bl[n] = *(const half8*)&lBl[cur][off];
    }
    #pragma unroll
    for (int m=0;m<4;m++)
      #pragma unroll
      for (int n=0;n<4;n++){
        acc[m][n] = __builtin_amdgcn_mfma_f32_16x16x32_f16(ah[m], bh[n], acc[m][n], 0,0,0);
        acc[m][n] = __builtin_amdgcn_mfma_f32_16x16x32_f16(al[m], bh[n], acc[m][n], 0,0,0);
        acc[m][n] = __builtin_amdgcn_mfma_f32_16x16x32_f16(ah[m], bl[n], acc[m][n], 0,0,0);
      }
    __syncthreads();
    cur ^= 1;
  }
  int m0 = (mb<<7)+(wr<<6), n0 = (nb<<7)+(wc<<6);
  #pragma unroll
  for (int m=0;m<4;m++)
    #pragma unroll
    for (int n=0;n<4;n++)
      #pragma unroll
      for (int i=0;i<4;i++){
        int R = m0+(m<<4)+(fg<<2)+i;
        int Cc = n0+(n<<4)+fr;
        float v = acc[m][n][i] * (1.f/1024.f);
        if (ADDX) v += addsrc[(size_t)R*N + Cc];
        out[(size_t)R*N + Cc] = v;
        if (vsplit && Cc >= 2048) vsplit[(size_t)R*1024 + (Cc-2048)] = v;
      }
}

// ---------------- plain fp16 GEMM, 2-phase prefetch pipeline, BK=32 ----------
// (32KB LDS; best for short-K shapes.) EPI: 0 store half, 1 relu^2 half,
// 2 scatter-add, 3 staged w*acc half. FUSED: blockIdx.y = expert. dmode 2:
// runtime-sized mb-major supertile over ACTIVE blocks.
template<int EPI, int FUSED>
__global__ __launch_bounds__(256) void gemm_h(
    const _Float16* __restrict__ A, const _Float16* __restrict__ A2, int Astride,
    const _Float16* __restrict__ Bw, _Float16* __restrict__ outH,
    float* __restrict__ outF, const int* __restrict__ list,
    const float* __restrict__ listw, const int* __restrict__ cntp,
    int M, int N, int K, int gmode, int cntMul, int Alim, int dmode,
    const int* __restrict__ offp)
{
  if (FUSED){
    int ez = blockIdx.y;
    cntp += ez;
    list += (ez<<13);
    if (listw) listw += (ez<<13);
    Bw += (size_t)ez * (size_t)N * (size_t)K;
    size_t so = (size_t)offp[ez];
    if (EPI == 1 || EPI == 3) outH += so * (size_t)N;
    if (EPI == 2 || EPI == 3) A += so * (size_t)Astride;
  }
  int Meff = M;
  if (cntp){ int cv = cntp[0]*cntMul; Meff = cv < M ? cv : M; }
  int nNB = N >> 7;
  int mb, nb;
  if (dmode == 2){
    int nMBa = (Meff + 127) >> 7;
    int T = nMBa * nNB;
    if ((int)blockIdx.x >= T) return;
    int swz = xcd_swz((int)blockIdx.x, T);
    mb = swz / nNB; nb = swz % nNB;
  } else {
    int bid = xcd_swz((int)blockIdx.x, (int)gridDim.x);
    decode_mb_nb(bid, nNB, M >> 7, dmode, mb, nb);
    if ((mb<<7) >= Meff) return;
  }
  __shared__ _Float16 lA[2][4096], lB[2][4096];
  int tid = threadIdx.x;
  int lane = tid & 63, wid = tid >> 6;
  int wr = wid >> 1, wc = wid & 1;
  int fr = lane & 15, fg = lane >> 4;
  f32x4 z = {0.f,0.f,0.f,0.f};
  f32x4 acc[4][4];
  #pragma unroll
  for (int m=0;m<4;m++)
    #pragma unroll
    for (int n=0;n<4;n++) acc[m][n] = z;

  size_t brow = (size_t)(nb<<7);
  int arow_s[2]; size_t boff_s[2]; int kcol_s[2]; int ldst_s[2];
  #pragma unroll
  for (int it=0; it<2; ++it){
    int q = (it<<8) + tid;
    int row = q >> 2, c = q & 3;
    int cg = c ^ ((row >> 1) & 3);       // BK=32 swizzle
    int gr = (mb<<7) + row;
    int grc = gr < (M-1) ? gr : (M-1);
    int sr2;
    if (gmode==0) sr2 = gr < (Meff-1) ? gr : (Meff-1);
    else if (gmode==1) sr2 = list[grc];
    else sr2 = (list[grc>>2]<<2) + (gr&3);
    sr2 = (sr2 < 0 || sr2 > Alim) ? 0 : sr2;
    arow_s[it] = sr2;
    kcol_s[it] = cg<<3;
    boff_s[it] = (brow+row)*K + (cg<<3);
    ldst_s[it] = q<<3;
  }

  auto STAGE = [&](int buf, int kt){
    #pragma unroll
    for (int it=0; it<2; ++it){
      int kloc = kt + kcol_s[it];
      const _Float16* asrc;
      if (A2 != nullptr && kloc >= 1024) asrc = A2 + (size_t)arow_s[it]*Astride + (kloc-1024);
      else asrc = A + (size_t)arow_s[it]*Astride + kloc;
      gload16(asrc, &lA[buf][ldst_s[it]]);
      gload16(Bw + boff_s[it] + kt, &lB[buf][ldst_s[it]]);
    }
  };

  STAGE(0, 0);
  __syncthreads();
  int nk = K >> 5, cur = 0;
  for (int ki=0; ki<nk; ++ki){
    if (ki+1 < nk) STAGE(cur^1, (ki+1)<<5);
    half8 af[4], bf[4];
    #pragma unroll
    for (int m=0;m<4;m++){
      int r = (wr<<6)+(m<<4)+fr;
      af[m] = *(const half8*)&lA[cur][(r<<5) + ((fg ^ ((r>>1)&3))<<3)];
    }
    #pragma unroll
    for (int n=0;n<4;n++){
      int r = (wc<<6)+(n<<4)+fr;
      bf[n] = *(const half8*)&lB[cur][(r<<5) + ((fg ^ ((r>>1)&3))<<3)];
    }
    #pragma unroll
    for (int m=0;m<4;m++)
      #pragma unroll
      for (int n=0;n<4;n++)
        acc[m][n] = __builtin_amdgcn_mfma_f32_16x16x32_f16(af[m], bf[n], acc[m][n], 0,0,0);
    __syncthreads();
    cur ^= 1;
  }
  int m0 = (mb<<7)+(wr<<6), n0 = (nb<<7)+(wc<<6);
  #pragma unroll
  for (int m=0;m<4;m++)
    #pragma unroll
    for (int n=0;n<4;n++)
      #pragma unroll
      for (int i=0;i<4;i++){
        int R = m0+(m<<4)+(fg<<2)+i;
        if (R >= Meff) continue;
        int Cc = n0+(n<<4)+fr;
        float v = acc[m][n][i];
        if (EPI == 0){
          outH[(size_t)R*N + Cc] = (_Float16)v;
        } else if (EPI == 1){
          v = v > 0.f ? v : 0.f;
          outH[(size_t)R*N + Cc] = (_Float16)(v*v);
        } else if (EPI == 3){
          outH[(size_t)R*N + Cc] = (_Float16)(listw[R]*v);
        } else {
          int tk = list[R];
          float add = listw[R]*v;
          if (FUSED) atomicAdd(&outF[(size_t)tk*N + Cc], add);
          else outF[(size_t)tk*N + Cc] += add;
        }
      }
}

// ---------------- plain fp16 GEMM, 2-phase pipeline, BK=64 (long-K: FFN2) ------
// KS: split-K factor via blockIdx.z; EPI==3 partials go to per-half stage slabs.
template<int EPI, int FUSED, int KS>
__global__ __launch_bounds__(256) void gemm_h64(
    const _Float16* __restrict__ A, const _Float16* __restrict__ A2, int Astride,
    const _Float16* __restrict__ Bw, _Float16* __restrict__ outH,
    float* __restrict__ outF, const int* __restrict__ list,
    const float* __restrict__ listw, const int* __restrict__ cntp,
    int M, int N, int K, int gmode, int cntMul, int Alim, int dmode,
    const int* __restrict__ offp)
{
  if (FUSED){
    int ez = blockIdx.y;
    cntp += ez;
    list += (ez<<13);
    if (listw) listw += (ez<<13);
    Bw += (size_t)ez * (size_t)N * (size_t)K;
    size_t so = (size_t)offp[ez];
    if (EPI == 1 || EPI == 3) outH += so * (size_t)N;
    if (EPI == 2 || EPI == 3) A += so * (size_t)Astride;
  }
  if (KS > 1 && EPI == 3) outH += (size_t)blockIdx.z * STAGE_SLAB;
  int kbeg = (KS > 1) ? (K/KS) * (int)blockIdx.z : 0;
  int Keff = K / KS;
  int Meff = M;
  if (cntp){ int cv = cntp[0]*cntMul; Meff = cv < M ? cv : M; }
  int nNB = N >> 7;
  int mb, nb;
  if (dmode == 2){
    int nMBa = (Meff + 127) >> 7;
    int T = nMBa * nNB;
    if ((int)blockIdx.x >= T) return;
    int swz = xcd_swz((int)blockIdx.x, T);
    mb = swz / nNB; nb = swz % nNB;
  } else {
    int bid = xcd_swz((int)blockIdx.x, (int)gridDim.x);
    decode_mb_nb(bid, nNB, M >> 7, dmode, mb, nb);
    if ((mb<<7) >= Meff) return;
  }
  __shared__ _Float16 lA[2][8192], lB[2][8192];
  int tid = threadIdx.x;
  int lane = tid & 63, wid = tid >> 6;
  int wr = wid >> 1, wc = wid & 1;
  int fr = lane & 15, fg = lane >> 4;
  f32x4 z = {0.f,0.f,0.f,0.f};
  f32x4 acc[4][4];
  #pragma unroll
  for (int m=0;m<4;m++)
    #pragma unroll
    for (int n=0;n<4;n++) acc[m][n] = z;

  size_t brow = (size_t)(nb<<7);
  int arow_s[4]; size_t boff_s[4]; int kcol_s[4];
  #pragma unroll
  for (int it=0; it<4; ++it){
    int q = (it<<8) + tid;
    int row = q >> 3, c8 = q & 7;
    int c8g = c8 ^ (row & 7);
    int gr = (mb<<7) + row;
    int grc = gr < (M-1) ? gr : (M-1);
    int sr2;
    if (gmode==0) sr2 = gr < (Meff-1) ? gr : (Meff-1);
    else if (gmode==1) sr2 = list[grc];
    else sr2 = (list[grc>>2]<<2) + (gr&3);
    sr2 = (sr2 < 0 || sr2 > Alim) ? 0 : sr2;
    arow_s[it] = sr2;
    kcol_s[it] = c8g<<3;
    boff_s[it] = (brow+row)*K + kbeg + (c8g<<3);
  }

  auto STAGE = [&](int buf, int kt){
    #pragma unroll
    for (int it=0; it<4; ++it){
      int q = (it<<8) + tid;
      int kloc = kbeg + kt + kcol_s[it];
      const _Float16* asrc;
      if (A2 != nullptr && kloc >= 1024) asrc = A2 + (size_t)arow_s[it]*Astride + (kloc-1024);
      else asrc = A + (size_t)arow_s[it]*Astride + kloc;
      gload16(asrc, &lA[buf][q<<3]);
      gload16(Bw + boff_s[it] + kt, &lB[buf][q<<3]);
    }
  };

  STAGE(0, 0);
  __syncthreads();
  int nk = Keff >> 6, cur = 0;
  for (int ki=0; ki<nk; ++ki){
    if (ki+1 < nk) STAGE(cur^1, (ki+1)<<6);
    #pragma unroll
    for (int kk2=0; kk2<2; ++kk2){
      int ko8 = (kk2<<2) + fg;
      half8 af[4], bf[4];
      #pragma unroll
      for (int m=0;m<4;m++){
        int r = (wr<<6)+(m<<4)+fr;
        af[m] = *(const half8*)&lA[cur][(r<<6) + ((ko8 ^ (r & 7))<<3)];
      }
      #pragma unroll
      for (int n=0;n<4;n++){
        int r = (wc<<6)+(n<<4)+fr;
        bf[n] = *(const half8*)&lB[cur][(r<<6) + ((ko8 ^ (r & 7))<<3)];
      }
      #pragma unroll
      for (int m=0;m<4;m++)
        #pragma unroll
        for (int n=0;n<4;n++)
          acc[m][n] = __builtin_amdgcn_mfma_f32_16x16x32_f16(af[m], bf[n], acc[m][n], 0,0,0);
    }
    __syncthreads();
    cur ^= 1;
  }
  int m0 = (mb<<7)+(wr<<6), n0 = (nb<<7)+(wc<<6);
  #pragma unroll
  for (int m=0;m<4;m++)
    #pragma unroll
    for (int n=0;n<4;n++)
      #pragma unroll
      for (int i=0;i<4;i++){
        int R = m0+(m<<4)+(fg<<2)+i;
        if (R >= Meff) continue;
        int Cc = n0+(n<<4)+fr;
        float v = acc[m][n][i];
        if (EPI == 0){
          outH[(size_t)R*N + Cc] = (_Float16)v;
        } else if (EPI == 1){
          v = v > 0.f ? v : 0.f;
          outH[(size_t)R*N + Cc] = (_Float16)(v*v);
        } else if (EPI == 3){
          outH[(size_t)R*N + Cc] = (_Float16)(listw[R]*v);
        } else {
          int tk = list[R];
          float add = listw[R]*v;
          if (FUSED || KS > 1) atomicAdd(&outF[(size_t)tk*N + Cc], add);
          else outF[(size_t)tk*N + Cc] += add;
        }
      }
}

// ---------------- FFN combine (no-atomic path): out0[t] += sum of staged rows ------
__global__ __launch_bounds__(256) void combine_ffn(
    const int* __restrict__ inv, const int* __restrict__ offp,
    const _Float16* __restrict__ stage, float* __restrict__ out0, int nsplit)
{
  int t = blockIdx.x, tid = threadIdx.x;
  float acc[4] = {0.f,0.f,0.f,0.f};
  #pragma unroll
  for (int s=0; s<2; ++s){
    int iv = inv[(t<<1)+s];
    int e = iv >> 13;
    if (e < 6){
      int p = iv & 8191;
      size_t row = (size_t)offp[e] + p;
      for (int zz=0; zz<nsplit; ++zz){
        const _Float16* sp = stage + (size_t)zz*STAGE_SLAB + row*1024 + tid*4;
        #pragma unroll
        for (int j=0;j<4;j++) acc[j] += (float)sp[j];
      }
    }
  }
  float* op = out0 + (size_t)t*1024 + tid*4;
  #pragma unroll
  for (int j=0;j<4;j++) op[j] += acc[j];
}

// ---------------- chunked RWKV scan: 3 passes (rkv fused input, stride 3072) -------
constexpr int SRD = 3072;

__global__ __launch_bounds__(64) void scan_passA(
    const float* __restrict__ rkv, const float* __restrict__ watt,
    float* __restrict__ states)
{
  const float* kb = rkv + 1024;
  const float* vb = rkv + 2048;
  int lane = threadIdx.x, bx = blockIdx.x;
  int chunk = bx & 15, bhq = bx >> 4;
  int b = bhq >> 6, h = (bhq >> 2) & 15, qq = bhq & 3;
  int dg = lane >> 4;
  int e = (qq<<4) + (lane & 15);
  float dec[16];
  #pragma unroll
  for (int i=0;i<16;i++){
    float wv = watt[(h<<6) + (dg<<4) + i];
    dec[i] = 1.f/(1.f + expf(-wv));
  }
  float st[16];
  #pragma unroll
  for (int i=0;i<16;i++) st[i]=0.f;
  __shared__ float sk[64];
  size_t rowbase = ((size_t)(b*1024 + chunk*64))*SRD + (h<<6);
  float pk[4], pv[4];
  #pragma unroll
  for (int j=0;j<4;j++){
    size_t o = rowbase + (size_t)j*SRD;
    pk[j]=kb[o+lane]; pv[j]=vb[o+e];
  }
  for (int t=0;t<64;t+=4){
    #pragma unroll
    for (int s4=0;s4<4;s4++){
      int tt = t+s4;
      sk[lane]=pk[s4];
      float ve = pv[s4];
      __syncthreads();
      if (tt+4 < 64){
        size_t o = rowbase + (size_t)(tt+4)*SRD;
        pk[s4]=kb[o+lane]; pv[s4]=vb[o+e];
      }
      const f32x4* K4 = (const f32x4*)&sk[dg<<4];
      #pragma unroll
      for (int j=0;j<4;j++){
        f32x4 kv = K4[j];
        #pragma unroll
        for (int ii=0;ii<4;ii++){
          int i=(j<<2)+ii;
          st[i] = st[i]*dec[i] + kv[ii]*ve;
        }
      }
      __syncthreads();
    }
  }
  float* sp = states + ((size_t)bhq*16 + chunk)*1024 + (lane<<4);
  #pragma unroll
  for (int i=0;i<16;i++) sp[i] = st[i];
}

__global__ __launch_bounds__(256) void scan_passB(
    float* __restrict__ states, const float* __restrict__ watt)
{
  int bhq = blockIdx.x;
  int h = (bhq >> 2) & 15;
  int t = threadIdx.x;
  int j0 = t*4;
  int d0 = ((j0>>8)<<4) + (j0&15);
  f32x4 wv = *(const f32x4*)(watt + (h<<6) + d0);
  f32x4 dec64;
  #pragma unroll
  for (int j=0;j<4;j++){
    float d = 1.f/(1.f + expf(-wv[j]));
    d = d*d; d = d*d; d = d*d; d = d*d; d = d*d; d = d*d;  // d^64
    dec64[j] = d;
  }
  f32x4 S = {0.f,0.f,0.f,0.f};
  float* base = states + (size_t)bhq*16*1024 + j0;
  for (int c=0;c<16;c++){
    f32x4 loc = *(f32x4*)(base + (size_t)c*1024);
    *(f32x4*)(base + (size_t)c*1024) = S;
    S = S*dec64 + loc;
  }
}

__global__ __launch_bounds__(64) void scan_passC(
    const float* __restrict__ rkv, const float* __restrict__ watt,
    const float* __restrict__ states,
    _Float16* __restrict__ outHi, _Float16* __restrict__ outLo)
{
  const float* rb = rkv;
  const float* kb = rkv + 1024;
  const float* vb = rkv + 2048;
  int lane = threadIdx.x, bx = blockIdx.x;
  int chunk = bx & 15, bhq = bx >> 4;
  int b = bhq >> 6, h = (bhq >> 2) & 15, qq = bhq & 3;
  int dg = lane >> 4;
  int e = (qq<<4) + (lane & 15);
  float dec[16];
  #pragma unroll
  for (int i=0;i<16;i++){
    float wv = watt[(h<<6) + (dg<<4) + i];
    dec[i] = 1.f/(1.f + expf(-wv));
  }
  float st[16];
  const float* sp = states + ((size_t)bhq*16 + chunk)*1024 + (lane<<4);
  #pragma unroll
  for (int i=0;i<16;i++) st[i] = sp[i];
  __shared__ float sk[64], sr[64];
  size_t rowbase = ((size_t)(b*1024 + chunk*64))*SRD + (h<<6);
  size_t obase   = ((size_t)(b*1024 + chunk*64))*1024 + (h<<6);
  float pk[4], pr[4], pv[4];
  #pragma unroll
  for (int j=0;j<4;j++){
    size_t o = rowbase + (size_t)j*SRD;
    pk[j]=kb[o+lane]; pr[j]=rb[o+lane]; pv[j]=vb[o+e];
  }
  for (int t=0;t<64;t+=4){
    #pragma unroll
    for (int s4=0;s4<4;s4++){
      int tt = t+s4;
      sk[lane]=pk[s4]; sr[lane]=pr[s4];
      float ve = pv[s4];
      __syncthreads();
      if (tt+4 < 64){
        size_t o = rowbase + (size_t)(tt+4)*SRD;
        pk[s4]=kb[o+lane]; pr[s4]=rb[o+lane]; pv[s4]=vb[o+e];
      }
      const f32x4* K4 = (const f32x4*)&sk[dg<<4];
      const f32x4* R4 = (const f32x4*)&sr[dg<<4];
      float p = 0.f;
      #pragma unroll
      for (int j=0;j<4;j++){
        f32x4 kv = K4[j], rv = R4[j];
        #pragma unroll
        for (int ii=0;ii<4;ii++){
          int i=(j<<2)+ii;
          st[i] = st[i]*dec[i] + kv[ii]*ve;
          p += rv[ii]*st[i];
        }
      }
      p += __shfl_xor(p, 16);
      p += __shfl_xor(p, 32);
      if (lane < 16){
        size_t o = obase + (size_t)tt*1024 + (qq<<4) + lane;
        float ps = p*16.f;
        _Float16 hi = (_Float16)ps;
        outHi[o] = hi;
        outLo[o] = (_Float16)(ps - (float)hi);
      }
      __syncthreads();
    }
  }
}

// ---------------- routing (64 tokens/block, block-aggregated atomics) ----------
// also records invPos[token*2+slot] = (expert<<13)|position for the combine pass.
__global__ __launch_bounds__(256) void routing_kernel(
    const float* __restrict__ hf, const float* __restrict__ Wcr,
    const float* __restrict__ Wct, const float* __restrict__ Wd,
    const float* __restrict__ Wa, const float* __restrict__ cap,
    int* __restrict__ cnt, int* __restrict__ listTok, float* __restrict__ listW,
    int* __restrict__ invPos)
{
  __shared__ int   lt[128];
  __shared__ int   le[128];
  __shared__ float lwv[128];
  int tid = threadIdx.x, wid = tid >> 6, lane = tid & 63;
  float cap8[8];
  #pragma unroll
  for (int e2=0;e2<8;e2++) cap8[e2] = cap[e2];

  for (int tt=0; tt<16; ++tt){
    int t = ((int)blockIdx.x<<6) + (wid<<4) + tt;
    const float* hrow = hf + (size_t)t*kC;
    float hr[16];
    #pragma unroll
    for (int i=0;i<16;i++) hr[i] = hrow[lane + (i<<6)];
    float dots[17];
    #pragma unroll
    for (int e2=0;e2<9;e2++){
      const float* wp = (e2<6) ? (Wcr + (size_t)e2*kC)
                    : (e2<8) ? (Wct + (size_t)(e2-6)*kC) : Wd;
      float a = 0.f;
      #pragma unroll
      for (int i=0;i<16;i++) a += hr[i]*wp[lane+(i<<6)];
      dots[e2] = a;
    }
    #pragma unroll
    for (int e2=0;e2<8;e2++){
      float a = 0.f;
      #pragma unroll
      for (int i=0;i<16;i++) a += hr[i]*Wa[(size_t)(lane+(i<<6))*8 + e2];
      dots[9+e2] = a;
    }
    #pragma unroll
    for (int e2=0;e2<17;e2++){
      float a = dots[e2];
      #pragma unroll
      for (int off=32; off; off>>=1) a += __shfl_xor(a, off);
      dots[e2] = a;
    }
    float diff = dots[8] > 20.f ? dots[8] : log1pf(expf(dots[8]));
    float am = dots[9];
    #pragma unroll
    for (int e2=1;e2<8;e2++) am = fmaxf(am, dots[9+e2]);
    float ee[8]; float es = 0.f;
    #pragma unroll
    for (int e2=0;e2<8;e2++){ ee[e2] = expf(dots[9+e2]-am); es += ee[e2]; }
    float inv = 1.f/es;
    float bids[8];
    #pragma unroll
    for (int e2=0;e2<8;e2++){
      float cf = 1.f/(1.f+expf(-dots[e2]));
      bids[e2] = cf*cap8[e2]*diff + ee[e2]*inv;
    }
    int i0=0; float v0=bids[0];
    #pragma unroll
    for (int e2=1;e2<8;e2++) if (bids[e2]>v0){ v0=bids[e2]; i0=e2; }
    int i1=-1; float v1=-1e30f;
    #pragma unroll
    for (int e2=0;e2<8;e2++) if (e2!=i0 && bids[e2]>v1){ v1=bids[e2]; i1=e2; }
    float x1 = expf(v1-v0);
    float w0 = 1.f/(1.f+x1);
    float w1 = x1/(1.f+x1);
    if (lane==0){
      int slot = (((wid<<4)+tt)<<1);
      lt[slot]   = t; le[slot]   = i0; lwv[slot]   = w0;
      lt[slot+1] = t; le[slot+1] = i1; lwv[slot+1] = w1;
    }
  }
  __syncthreads();
  if (tid < 8){
    int c = 0;
    for (int j=0;j<128;j++) c += (le[j]==tid) ? 1 : 0;
    int b = atomicAdd(&cnt[tid], c);
    for (int j=0;j<128;j++){
      if (le[j]==tid){
        listTok[(tid<<13)+b] = lt[j];
        listW[(tid<<13)+b]  = lwv[j];
        invPos[(lt[j]<<1) + (j&1)] = (tid<<13) + b;
        ++b;
      }
    }
  }
}

// ---------------- transformer-expert attention (P=4 prefix) ----------------
__global__ __launch_bounds__(256) void attn_logits(
    const _Float16* __restrict__ q, const _Float16* __restrict__ kp,
    float* __restrict__ attw, const int* __restrict__ cntp)
{
  int cnt = cntp[0];
  int gw = ((int)blockIdx.x<<2) + (threadIdx.x>>6);
  int r = gw >> 4, h = gw & 15;
  if (r >= cnt) return;
  int lane = threadIdx.x & 63;
  float qd = (float)q[(size_t)r*kC + (h<<6) + lane];
  float lg[4];
  #pragma unroll
  for (int p=0;p<4;p++){
    float kd = (float)kp[((size_t)(r<<2)+p)*kC + (h<<6) + lane];
    float a = qd*kd;
    #pragma unroll
    for (int off=32; off; off>>=1) a += __shfl_xor(a, off);
    lg[p] = a*0.125f;
  }
  float mx = fmaxf(fmaxf(lg[0],lg[1]),fmaxf(lg[2],lg[3]));
  float ex[4]; float s = 0.f;
  #pragma unroll
  for (int p=0;p<4;p++){ ex[p] = expf(lg[p]-mx); s += ex[p]; }
  float inv = 1.f/s;
  if (lane < 4){
    float pv_ = (lane==0) ? ex[0] : (lane==1) ? ex[1] : (lane==2) ? ex[2] : ex[3];
    attw[((size_t)r<<6) + (h<<2) + lane] = pv_*inv;
  }
}

__global__ __launch_bounds__(256) void attn_av(
    const float* __restrict__ attw, const _Float16* __restrict__ vp,
    _Float16* __restrict__ o, const int* __restrict__ cntp)
{
  int cnt = cntp[0];
  int idx = (int)blockIdx.x*256 + threadIdx.x;
  int r = idx >> 10;
  if (r >= cnt) return;
  int c = idx & 1023; int h = c >> 6;
  const float* aw = attw + ((size_t)r<<6) + (h<<2);
  float s = 0.f;
  #pragma unroll
  for (int p=0;p<4;p++) s += aw[p] * (float)vp[((size_t)(r<<2)+p)*kC + c];
  o[(size_t)r*kC + c] = (_Float16)s;
}

// ---------------- launch ----------------
extern "C" void kernel_launch(void* const* d_in, const int* in_sizes, int n_in,
                              void* d_out, int out_size, void* d_ws, size_t ws_size,
                              hipStream_t stream) {
  if (ws_size < WS_NEED) return;
  const bool bigws  = (ws_size >= WS_BIG);
  const bool split2 = (ws_size >= WS_SPLIT);
  const float* x    = (const float*)d_in[0];
  const float* cap  = (const float*)d_in[2];
  const float* g1   = (const float*)d_in[3];
  const float* b1   = (const float*)d_in[4];
  const float* g2   = (const float*)d_in[5];
  const float* b2   = (const float*)d_in[6];
  const float* Wr   = (const float*)d_in[7];
  const float* Wk   = (const float*)d_in[8];
  const float* Wv   = (const float*)d_in[9];
  const float* Wo   = (const float*)d_in[10];
  const float* watt = (const float*)d_in[11];
  const float* Wb   = (const float*)d_in[12];
  const float* Wkf  = (const float*)d_in[13];
  const float* Wvf  = (const float*)d_in[14];
  const float* Wcr  = (const float*)d_in[15];
  const float* Wqt  = (const float*)d_in[16];
  const float* Wkt  = (const float*)d_in[17];
  const float* Wvt  = (const float*)d_in[18];
  const float* Wot  = (const float*)d_in[19];
  const float* Wct  = (const float*)d_in[20];
  const float* Wd   = (const float*)d_in[21];
  const float* Wa   = (const float*)d_in[22];

  float* out0 = (float*)d_out;
  float* vout = out0 + CB;
  char* w = (char*)d_ws;
  _Float16* W1h  = (_Float16*)(w+O_W1H);
  _Float16* W1l  = (_Float16*)(w+O_W1L);
  _Float16* WoTh = (_Float16*)(w+O_WOH); _Float16* WoTl = (_Float16*)(w+O_WOL);
  _Float16* WbT  = (_Float16*)(w+O_WBT);
  _Float16* WkfT = (_Float16*)(w+O_WKF);
  _Float16* WvfT = (_Float16*)(w+O_WVF);
  _Float16* WqtT = (_Float16*)(w+O_WQT);
  _Float16* WktT = (_Float16*)(w+O_WKT);
  _Float16* WvtT = (_Float16*)(w+O_WVT);
  _Float16* WotT = (_Float16*)(w+O_WOT);
  _Float16* xlnHi= (_Float16*)(w+O_XH);
  _Float16* xlnLo= (_Float16*)(w+O_XL);
  float*    rkv  = (float*)(w+O_RKV);
  float*    stbuf= (float*)(w+O_XH);
  _Float16* rwHi = (_Float16*)(w+O_RWH);
  _Float16* rwLo = (_Float16*)(w+O_RWL);
  float*    hF   = (float*)(w+O_RKV);
  _Float16* hH   = (_Float16*)(w+O_RWL);
  _Float16* kkpool = (_Float16*)(w+O_XH);       // [144,272) during FFN
  _Float16* pfxE = (_Float16*)(w+O_XH);         // per-expert prefix [144,208)
  _Float16* kvE  = (_Float16*)(w+O_RKV+32*MB1); // kp/vp time-share [208,272)
  _Float16* pfxD = (_Float16*)(w+O_RKV+32*MB1); // dense prefix (fallback) [208,272)
  _Float16* kpF  = (_Float16*)(w+O_XH);         // fallback kp/vp [144,208)
  float*    attw = (float*)(w+O_AW);
  int*      cnt  = (int*)(w+O_CNT);
  int*      offp = (int*)(w+O_OFF);
  int*   listTok = (int*)(w+O_LTOK);
  float* listW   = (float*)(w+O_LW);
  int*   invPos  = (int*)(w+O_INV);
  _Float16* stageH = (_Float16*)(w+O_STAGE);
  // bigws: q/o live in the stage region (dead after combine) so rwHi survives
  _Float16* qH = bigws ? stageH            : (_Float16*)(w+O_RWH);
  _Float16* oH = bigws ? stageH + 8388608  : (_Float16*)(w+O_RWH);

  dim3 TB(256);
  zero_cnt<<<1,64,0,stream>>>(cnt);

  // weight transposes (+x64 hi/lo split for stage-1; QKV stacked [3072][1024])
  transpose_cvt<<<dim3(32,32,1),TB,0,stream>>>(Wr, W1h,           W1l,           1024,1024, 64.f,64.f,1024, 1);
  transpose_cvt<<<dim3(32,32,1),TB,0,stream>>>(Wk, W1h+1024*1024, W1l+1024*1024, 1024,1024, 64.f,64.f,1024, 1);
  transpose_cvt<<<dim3(32,32,1),TB,0,stream>>>(Wv, W1h+2048*1024, W1l+2048*1024, 1024,1024, 64.f,64.f,1024, 1);
  transpose_cvt<<<dim3(32,32,1),TB,0,stream>>>(Wo, WoTh, WoTl, 1024,1024, 64.f,64.f,1024, 1);
  transpose_cvt<<<dim3(128,64,1),TB,0,stream>>>(Wb,  WbT,  nullptr, 2048,4096, 1.f, 1.f/16.f, 1024, 0);
  transpose_cvt<<<dim3(128,32,6),TB,0,stream>>>(Wkf, WkfT, nullptr, 1024,4096, 1.f,1.f,9999, 0);
  transpose_cvt<<<dim3(32,128,6),TB,0,stream>>>(Wvf, WvfT, nullptr, 4096,1024, 1.f,1.f,9999, 0);
  transpose_cvt<<<dim3(32,32,2),TB,0,stream>>>(Wqt, WqtT, nullptr, 1024,1024, 1.f,1.f,9999, 0);
  transpose_cvt<<<dim3(32,32,2),TB,0,stream>>>(Wkt, WktT, nullptr, 1024,1024, 1.f,1.f,9999, 0);
  transpose_cvt<<<dim3(32,32,2),TB,0,stream>>>(Wvt, WvtT, nullptr, 1024,1024, 1.f,1.f,9999, 0);
  transpose_cvt<<<dim3(32,32,2),TB,0,stream>>>(Wot, WotT, nullptr, 1024,1024, 1.f,1.f,9999, 0);

  // stage 1: fused r|k|v emulated GEMM (N=3072), v-columns also -> v_first output
  ln_kernel<<<8192,TB,0,stream>>>(x, g1, b1, nullptr, nullptr, xlnHi, xlnLo, 16.f);
  gemm_emu<0><<<1536,TB,0,stream>>>(xlnHi, xlnLo, W1h, W1l, rkv, nullptr, vout,
                                    8192, 3072, 1024);
  scan_passA<<<8192,64,0,stream>>>(rkv, watt, stbuf);
  scan_passB<<<512,256,0,stream>>>(stbuf, watt);
  scan_passC<<<8192,64,0,stream>>>(rkv, watt, stbuf, rwHi, rwLo);
  gemm_emu<1><<<512,TB,0,stream>>>(rwHi, rwLo, WoTh, WoTl, out0, x, nullptr,
                                   8192, 1024, 1024);
  ln_kernel<<<8192,TB,0,stream>>>(out0, g2, b2, hF, hH, nullptr, nullptr, 1.f);

  // routing (block-aggregated atomics; records inverse map) + kk segment offsets
  routing_kernel<<<128,TB,0,stream>>>(hF, Wcr, Wct, Wd, Wa, cap, cnt, listTok, listW, invPos);
  calc_off<<<1,64,0,stream>>>(cnt, offp);

  // 6 SparseRWKVFFN experts, fused across experts, dmode=2.
  // FFN1 (K=1024): BK=32. FFN2 (K=4096): BK=64 (+split-K x2 when workspace allows).
  gemm_h<1,1><<<dim3(2048,6),TB,0,stream>>>(hH, nullptr, 1024, WkfT, kkpool,
                                  nullptr, listTok, nullptr, cnt,
                                  8192, 4096, 1024, 1, 1, 8191, 2, offp);
  if (bigws){
    if (split2){
      gemm_h64<3,1,2><<<dim3(512,6,2),TB,0,stream>>>(kkpool, nullptr, 4096, WvfT, stageH,
                                      nullptr, listTok, listW, cnt,
                                      8192, 1024, 4096, 0, 1, 8191, 2, offp);
      combine_ffn<<<8192,TB,0,stream>>>(invPos, offp, stageH, out0, 2);
    } else {
      gemm_h64<3,1,1><<<dim3(512,6),TB,0,stream>>>(kkpool, nullptr, 4096, WvfT, stageH,
                                      nullptr, listTok, listW, cnt,
                                      8192, 1024, 4096, 0, 1, 8191, 2, offp);
      combine_ffn<<<8192,TB,0,stream>>>(invPos, offp, stageH, out0, 1);
    }
  } else {
    gemm_h64<2,1,1><<<dim3(512,6),TB,0,stream>>>(kkpool, nullptr, 4096, WvfT, nullptr,
                                    out0, listTok, listW, cnt,
                                    8192, 1024, 4096, 0, 1, 8191, 2, offp);
  }

  if (bigws){
    // per-expert gathered prefix; q/o in stage region (rwHi stays intact)
    for (int e = 0; e < 2; ++e){
      int ge = 6 + e;
      gemm_h<0,0><<<64*32,TB,0,stream>>>(hH, rwHi, 1024, WbT, pfxE, nullptr,
                                      listTok+ge*8192, nullptr, cnt+ge,
                                      8192, 4096, 2048, 1, 1, 8191, 2, nullptr);
      gemm_h<0,0><<<64*8,TB,0,stream>>>(hH, nullptr, 1024, WqtT + (size_t)e*kC*kC, qH,
                                      nullptr, listTok+ge*8192, nullptr, cnt+ge,
                                      8192, 1024, 1024, 1, 1, 8191, 2, nullptr);
      gemm_h<0,0><<<256*8,TB,0,stream>>>(pfxE, nullptr, 1024, WktT + (size_t)e*kC*kC, kvE,
                                       nullptr, listTok+ge*8192, nullptr, cnt+ge,
                                       32768, 1024, 1024, 0, 4, 32767, 2, nullptr);
      attn_logits<<<32768,TB,0,stream>>>(qH, kvE, attw, cnt+ge);
      gemm_h<0,0><<<256*8,TB,0,stream>>>(pfxE, nullptr, 1024, WvtT + (size_t)e*kC*kC, kvE,
                                       nullptr, listTok+ge*8192, nullptr, cnt+ge,
                                       32768, 1024, 1024, 0, 4, 32767, 2, nullptr);
      attn_av<<<32768,TB,0,stream>>>(attw, kvE, oH, cnt+ge);
      gemm_h<2,0><<<64*8,TB,0,stream>>>(oH, nullptr, 1024, WotT + (size_t)e*kC*kC, nullptr,
                                      out0, listTok+ge*8192, listW+ge*8192, cnt+ge,
                                      8192, 1024, 1024, 0, 1, 8191, 2, nullptr);
    }
  } else {
    // fallback (round-13/14 semantics): dense prefix once, then gathered kp/vp.
    gemm_h<0,0><<<64*32,TB,0,stream>>>(hH, rwHi, 1024, WbT, pfxD, nullptr,
                                     nullptr, nullptr, nullptr, 8192, 4096, 2048, 0, 1, 8191, 0, nullptr);
    for (int e = 0; e < 2; ++e){
      int ge = 6 + e;
      gemm_h<0,0><<<64*8,TB,0,stream>>>(hH, nullptr, 1024, WqtT + (size_t)e*kC*kC, qH,
                                      nullptr, listTok+ge*8192, nullptr, cnt+ge,
                                      8192, 1024, 1024, 1, 1, 8191, 2, nullptr);
      gemm_h<0,0><<<256*8,TB,0,stream>>>(pfxD, nullptr, 1024, WktT + (size_t)e*kC*kC, kpF,
                                       nullptr, listTok+ge*8192, nullptr, cnt+ge,
                                       32768, 1024, 1024, 2, 4, 32767, 2, nullptr);
      attn_logits<<<32768,TB,0,stream>>>(qH, kpF, attw, cnt+ge);
      gemm_h<0,0><<<256*8,TB,0,stream>>>(pfxD, nullptr, 1024, WvtT + (size_t)e*kC*kC, kpF,
                                       nullptr, listTok+ge*8192, nullptr, cnt+ge,
                                       32768, 1024, 1024, 2, 4, 32767, 2, nullptr);
      attn_av<<<32768,TB,0,stream>>>(attw, kpF, oH, cnt+ge);
      gemm_h<2,0><<<64*8,TB,0,stream>>>(oH, nullptr, 1024, WotT + (size_t)e*kC*kC, nullptr,
                                      out0, listTok+ge*8192, listW+ge*8192, cnt+ge,
                                      8192, 1024, 1024, 0, 1, 8191, 2, nullptr);
    }
  }
}

// Round 21
// 1446.751 us; speedup vs baseline: 1.0182x; 1.0182x over previous
//
#include <hip/hip_runtime.h>

typedef float f32x4 __attribute__((ext_vector_type(4)));
typedef _Float16 half8 __attribute__((ext_vector_type(8)));

constexpr int kC  = 1024;
constexpr int kFF = 4096;
constexpr size_t MB1 = 1ull << 20;
constexpr long long CB = 8388608ll;   // 8192*1024

// ---------------- workspace layout (bytes) ----------------
constexpr size_t O_W1H = 0;          // QKV^T hi [3072][1024] half (x64)
constexpr size_t O_W1L = 6*MB1;      // QKV^T lo
constexpr size_t O_WOH = 12*MB1;     // Wo^T hi
constexpr size_t O_WOL = 14*MB1;     // Wo^T lo
constexpr size_t O_WBT = 16*MB1;     // WbT [4096][2048] half (rows k>=1024 prescaled 1/16)
constexpr size_t O_WKF = 32*MB1;     // 6 x [4096][1024] half
constexpr size_t O_WVF = 80*MB1;     // 6 x [1024][4096] half
constexpr size_t O_WQT = 128*MB1;    // 2 x [1024][1024] half each
constexpr size_t O_WKT = 132*MB1;
constexpr size_t O_WVT = 136*MB1;
constexpr size_t O_WOT = 140*MB1;
constexpr size_t O_XH  = 144*MB1;    // xlnHi; later stbuf; later kkpool [144,272); later pfx_e [144,208)
constexpr size_t O_XL  = 160*MB1;    // xlnLo
constexpr size_t O_RKV = 176*MB1;    // rkv f32 [8192][3072]; later hF; kk tail; kp/vp [208,272)
constexpr size_t O_RWH = 272*MB1;    // rwkvHi (x16) half (LIVE through transformer experts in bigws path)
constexpr size_t O_RWL = 288*MB1;    // rwkvLo half; later hH
constexpr size_t O_AW  = 304*MB1;    // attw f32 [8192][64]
constexpr size_t O_CNT = 306*MB1;
constexpr size_t O_OFF = O_CNT + 256;
constexpr size_t O_LTOK = O_CNT + 1024;
constexpr size_t O_LW   = O_LTOK + 8ull*8192*sizeof(int);
constexpr size_t O_INV  = O_LW + 8ull*8192*sizeof(float);
constexpr size_t WS_NEED = O_INV + 2ull*8192*sizeof(int) + 1024;
// optional no-atomic FFN2 stage (guarded by ws_size); reused for q/o after combine
constexpr size_t O_STAGE = 308*MB1;  // [16384][1024] half = 32MB
constexpr size_t WS_BIG  = 340*MB1;

__device__ __forceinline__ void gload16(const _Float16* g, _Float16* l){
  __builtin_amdgcn_global_load_lds(
      (const __attribute__((address_space(1))) void*)g,
      (__attribute__((address_space(3))) void*)l, 16, 0, 0);
}

// bijective XCD-aware block swizzle (m204): contiguous chunk per XCD
__device__ __forceinline__ int xcd_swz(int bid, int nwg){
  int q = nwg >> 3, r = nwg & 7;
  int x = bid & 7, i = bid >> 3;
  return (x < r ? x*(q+1) : r*(q+1) + (x-r)*q) + i;
}

// dmode 0: supertiled (dense); dmode 1: mb-fast.
__device__ __forceinline__ void decode_mb_nb(int bid, int nNB, int nMB, int dmode,
                                             int& mb, int& nb){
  if (dmode == 0){
    int m8 = bid & 7;
    int t = bid >> 3;
    nb = t % nNB;
    mb = m8 * (nMB >> 3) + t / nNB;
  } else {
    mb = bid % nMB;
    nb = bid / nMB;
  }
}

// ---------------- small kernels ----------------
__global__ void zero_cnt(int* c){ if (threadIdx.x < 8) c[threadIdx.x] = 0; }

__global__ void calc_off(const int* __restrict__ cnt, int* __restrict__ off){
  if (threadIdx.x == 0){
    int s = 0;
    for (int e = 0; e < 6; ++e){ off[e] = s; s += cnt[e]; }
  }
}

// out[c][r] = in[r][c] * (r<splitR ? sc1 : sc2), half (optional hi/lo split)
__global__ __launch_bounds__(256) void transpose_cvt(
    const float* __restrict__ in, _Float16* __restrict__ outHi,
    _Float16* __restrict__ outLo, int R, int C, float sc1, float sc2,
    int splitR, int split)
{
  __shared__ float tile[32][33];
  size_t zoff = (size_t)blockIdx.z * R * C;
  const float* ip = in + zoff;
  _Float16* oh = outHi + zoff;
  _Float16* ol = outLo ? outLo + zoff : nullptr;
  int c0 = blockIdx.x*32, r0 = blockIdx.y*32;
  int tx = threadIdx.x & 31, ty = threadIdx.x >> 5;
  #pragma unroll
  for (int j = 0; j < 32; j += 8){
    int r = r0+ty+j;
    float s = (r < splitR) ? sc1 : sc2;
    tile[ty+j][tx] = ip[(size_t)r*C + c0+tx] * s;
  }
  __syncthreads();
  #pragma unroll
  for (int j = 0; j < 32; j += 8){
    float v = tile[tx][ty+j];
    _Float16 hi = (_Float16)v;
    oh[(size_t)(c0+ty+j)*R + r0+tx] = hi;
    if (split) ol[(size_t)(c0+ty+j)*R + r0+tx] = (_Float16)(v - (float)hi);
  }
}

// LayerNorm rows of 1024.
__global__ __launch_bounds__(256) void ln_kernel(
    const float* __restrict__ x, const float* __restrict__ g,
    const float* __restrict__ b, float* __restrict__ yF,
    _Float16* __restrict__ yH, _Float16* __restrict__ yHi,
    _Float16* __restrict__ yLo, float fscale)
{
  int row = blockIdx.x, tid = threadIdx.x;
  int lane = tid & 63, wid = tid >> 6;
  __shared__ float red[2][4];
  f32x4 v = ((const f32x4*)(x + (size_t)row*kC))[tid];
  float s = v[0]+v[1]+v[2]+v[3];
  #pragma unroll
  for (int off=32; off; off>>=1) s += __shfl_xor(s, off);
  if (lane==0) red[0][wid] = s;
  __syncthreads();
  float mean = (red[0][0]+red[0][1]+red[0][2]+red[0][3]) * (1.f/1024.f);
  float d0=v[0]-mean, d1=v[1]-mean, d2=v[2]-mean, d3=v[3]-mean;
  float s2 = d0*d0+d1*d1+d2*d2+d3*d3;
  #pragma unroll
  for (int off=32; off; off>>=1) s2 += __shfl_xor(s2, off);
  if (lane==0) red[1][wid] = s2;
  __syncthreads();
  float var = (red[1][0]+red[1][1]+red[1][2]+red[1][3]) * (1.f/1024.f);
  float rs = 1.f / sqrtf(var + 1e-5f);
  f32x4 gg = ((const f32x4*)g)[tid];
  f32x4 bb = ((const f32x4*)b)[tid];
  float y[4];
  y[0] = d0*rs*gg[0]+bb[0];
  y[1] = d1*rs*gg[1]+bb[1];
  y[2] = d2*rs*gg[2]+bb[2];
  y[3] = d3*rs*gg[3]+bb[3];
  size_t base = (size_t)row*kC + tid*4;
  if (yF){
    f32x4 o = {y[0],y[1],y[2],y[3]};
    *(f32x4*)(yF + base) = o;
  }
  if (yH){
    #pragma unroll
    for (int j=0;j<4;j++) yH[base+j] = (_Float16)y[j];
  }
  if (yHi){
    #pragma unroll
    for (int j=0;j<4;j++){
      float ys = y[j]*fscale;
      _Float16 hi = (_Float16)ys;
      yHi[base+j] = hi;
      yLo[base+j] = (_Float16)(ys - (float)hi);
    }
  }
}

// ---------------- fp16-pair emulated "f32" GEMM, 2-phase pipeline, BK=32 ----------
template<int ADDX>
__global__ __launch_bounds__(256) void gemm_emu(
    const _Float16* __restrict__ Ah, const _Float16* __restrict__ Al,
    const _Float16* __restrict__ Bh, const _Float16* __restrict__ Bl,
    float* __restrict__ out, const float* __restrict__ addsrc,
    float* __restrict__ vsplit, int M, int N, int K)
{
  __shared__ _Float16 lAh[2][4096], lAl[2][4096], lBh[2][4096], lBl[2][4096];
  int bid = xcd_swz((int)blockIdx.x, (int)gridDim.x);
  int mb, nb;
  decode_mb_nb(bid, N >> 7, M >> 7, 0, mb, nb);
  int tid = threadIdx.x;
  int lane = tid & 63, wid = tid >> 6;
  int wr = wid >> 1, wc = wid & 1;
  int fr = lane & 15, fg = lane >> 4;
  f32x4 z = {0.f,0.f,0.f,0.f};
  f32x4 acc[4][4];
  #pragma unroll
  for (int m=0;m<4;m++)
    #pragma unroll
    for (int n=0;n<4;n++) acc[m][n] = z;

  size_t arow = (size_t)(mb<<7), brow = (size_t)(nb<<7);
  size_t aoff_s[2], boff_s[2]; int ldst_s[2];
  #pragma unroll
  for (int it=0; it<2; ++it){
    int q = (it<<8) + tid;
    int row = q >> 2, c = q & 3;
    int cg = c ^ ((row >> 1) & 3);       // pre-swizzled source chunk
    aoff_s[it] = (arow+row)*K + (cg<<3);
    boff_s[it] = (brow+row)*K + (cg<<3);
    ldst_s[it] = q<<3;
  }
  auto STAGE = [&](int buf, int kt){
    #pragma unroll
    for (int it=0; it<2; ++it){
      gload16(Ah + aoff_s[it] + kt, &lAh[buf][ldst_s[it]]);
      gload16(Al + aoff_s[it] + kt, &lAl[buf][ldst_s[it]]);
      gload16(Bh + boff_s[it] + kt, &lBh[buf][ldst_s[it]]);
      gload16(Bl + boff_s[it] + kt, &lBl[buf][ldst_s[it]]);
    }
  };

  STAGE(0, 0);
  __syncthreads();
  int nk = K >> 5, cur = 0;
  for (int ki=0; ki<nk; ++ki){
    if (ki+1 < nk) STAGE(cur^1, (ki+1)<<5);
    half8 ah[4], al[4], bh[4], bl[4];
    #pragma unroll
    for (int m=0;m<4;m++){
      int r = (wr<<6)+(m<<4)+fr;
      int off = (r<<5) + ((fg ^ ((r>>1)&3))<<3);
      ah[m] = *(const half8*)&lAh[cur][off];
      al[m] = *(const half8*)&lAl[cur][off];
    }
    #pragma unroll
    for (int n=0;n<4;n++){
      int r = (wc<<6)+(n<<4)+fr;
      int off = (r<<5) + ((fg ^ ((r>>1)&3))<<3);
      bh[n] = *(const half8*)&lBh[cur][off];
      bl[n] = *(const half8*)&lBl[cur][off];
    }
    #pragma unroll
    for (int m=0;m<4;m++)
      #pragma unroll
      for (int n=0;n<4;n++){
        acc[m][n] = __builtin_amdgcn_mfma_f32_16x16x32_f16(ah[m], bh[n], acc[m][n], 0,0,0);
        acc[m][n] = __builtin_amdgcn_mfma_f32_16x16x32_f16(al[m], bh[n], acc[m][n], 0,0,0);
        acc[m][n] = __builtin_amdgcn_mfma_f32_16x16x32_f16(ah[m], bl[n], acc[m][n], 0,0,0);
      }
    __syncthreads();
    cur ^= 1;
  }
  int m0 = (mb<<7)+(wr<<6), n0 = (nb<<7)+(wc<<6);
  #pragma unroll
  for (int m=0;m<4;m++)
    #pragma unroll
    for (int n=0;n<4;n++)
      #pragma unroll
      for (int i=0;i<4;i++){
        int R = m0+(m<<4)+(fg<<2)+i;
        int Cc = n0+(n<<4)+fr;
        float v = acc[m][n][i] * (1.f/1024.f);
        if (ADDX) v += addsrc[(size_t)R*N + Cc];
        out[(size_t)R*N + Cc] = v;
        if (vsplit && Cc >= 2048) vsplit[(size_t)R*1024 + (Cc-2048)] = v;
      }
}

// ---------------- plain fp16 GEMM, 2-phase prefetch pipeline, BK=32 ----------
// (32KB LDS; best for short-K shapes.) EPI: 0 store half, 1 relu^2 half,
// 2 scatter-add, 3 staged w*acc half. FUSED: blockIdx.y = expert. dmode 2:
// runtime-sized mb-major supertile over ACTIVE blocks.
template<int EPI, int FUSED>
__global__ __launch_bounds__(256) void gemm_h(
    const _Float16* __restrict__ A, const _Float16* __restrict__ A2, int Astride,
    const _Float16* __restrict__ Bw, _Float16* __restrict__ outH,
    float* __restrict__ outF, const int* __restrict__ list,
    const float* __restrict__ listw, const int* __restrict__ cntp,
    int M, int N, int K, int gmode, int cntMul, int Alim, int dmode,
    const int* __restrict__ offp)
{
  if (FUSED){
    int ez = blockIdx.y;
    cntp += ez;
    list += (ez<<13);
    if (listw) listw += (ez<<13);
    Bw += (size_t)ez * (size_t)N * (size_t)K;
    size_t so = (size_t)offp[ez];
    if (EPI == 1 || EPI == 3) outH += so * (size_t)N;
    if (EPI == 2 || EPI == 3) A += so * (size_t)Astride;
  }
  int Meff = M;
  if (cntp){ int cv = cntp[0]*cntMul; Meff = cv < M ? cv : M; }
  int nNB = N >> 7;
  int mb, nb;
  if (dmode == 2){
    int nMBa = (Meff + 127) >> 7;
    int T = nMBa * nNB;
    if ((int)blockIdx.x >= T) return;
    int swz = xcd_swz((int)blockIdx.x, T);
    mb = swz / nNB; nb = swz % nNB;
  } else {
    int bid = xcd_swz((int)blockIdx.x, (int)gridDim.x);
    decode_mb_nb(bid, nNB, M >> 7, dmode, mb, nb);
    if ((mb<<7) >= Meff) return;
  }
  __shared__ _Float16 lA[2][4096], lB[2][4096];
  int tid = threadIdx.x;
  int lane = tid & 63, wid = tid >> 6;
  int wr = wid >> 1, wc = wid & 1;
  int fr = lane & 15, fg = lane >> 4;
  f32x4 z = {0.f,0.f,0.f,0.f};
  f32x4 acc[4][4];
  #pragma unroll
  for (int m=0;m<4;m++)
    #pragma unroll
    for (int n=0;n<4;n++) acc[m][n] = z;

  size_t brow = (size_t)(nb<<7);
  int arow_s[2]; size_t boff_s[2]; int kcol_s[2]; int ldst_s[2];
  #pragma unroll
  for (int it=0; it<2; ++it){
    int q = (it<<8) + tid;
    int row = q >> 2, c = q & 3;
    int cg = c ^ ((row >> 1) & 3);       // BK=32 swizzle
    int gr = (mb<<7) + row;
    int grc = gr < (M-1) ? gr : (M-1);
    int sr2;
    if (gmode==0) sr2 = gr < (Meff-1) ? gr : (Meff-1);
    else if (gmode==1) sr2 = list[grc];
    else sr2 = (list[grc>>2]<<2) + (gr&3);
    sr2 = (sr2 < 0 || sr2 > Alim) ? 0 : sr2;
    arow_s[it] = sr2;
    kcol_s[it] = cg<<3;
    boff_s[it] = (brow+row)*K + (cg<<3);
    ldst_s[it] = q<<3;
  }

  auto STAGE = [&](int buf, int kt){
    #pragma unroll
    for (int it=0; it<2; ++it){
      int kloc = kt + kcol_s[it];
      const _Float16* asrc;
      if (A2 != nullptr && kloc >= 1024) asrc = A2 + (size_t)arow_s[it]*Astride + (kloc-1024);
      else asrc = A + (size_t)arow_s[it]*Astride + kloc;
      gload16(asrc, &lA[buf][ldst_s[it]]);
      gload16(Bw + boff_s[it] + kt, &lB[buf][ldst_s[it]]);
    }
  };

  STAGE(0, 0);
  __syncthreads();
  int nk = K >> 5, cur = 0;
  for (int ki=0; ki<nk; ++ki){
    if (ki+1 < nk) STAGE(cur^1, (ki+1)<<5);
    half8 af[4], bf[4];
    #pragma unroll
    for (int m=0;m<4;m++){
      int r = (wr<<6)+(m<<4)+fr;
      af[m] = *(const half8*)&lA[cur][(r<<5) + ((fg ^ ((r>>1)&3))<<3)];
    }
    #pragma unroll
    for (int n=0;n<4;n++){
      int r = (wc<<6)+(n<<4)+fr;
      bf[n] = *(const half8*)&lB[cur][(r<<5) + ((fg ^ ((r>>1)&3))<<3)];
    }
    #pragma unroll
    for (int m=0;m<4;m++)
      #pragma unroll
      for (int n=0;n<4;n++)
        acc[m][n] = __builtin_amdgcn_mfma_f32_16x16x32_f16(af[m], bf[n], acc[m][n], 0,0,0);
    __syncthreads();
    cur ^= 1;
  }
  int m0 = (mb<<7)+(wr<<6), n0 = (nb<<7)+(wc<<6);
  #pragma unroll
  for (int m=0;m<4;m++)
    #pragma unroll
    for (int n=0;n<4;n++)
      #pragma unroll
      for (int i=0;i<4;i++){
        int R = m0+(m<<4)+(fg<<2)+i;
        if (R >= Meff) continue;
        int Cc = n0+(n<<4)+fr;
        float v = acc[m][n][i];
        if (EPI == 0){
          outH[(size_t)R*N + Cc] = (_Float16)v;
        } else if (EPI == 1){
          v = v > 0.f ? v : 0.f;
          outH[(size_t)R*N + Cc] = (_Float16)(v*v);
        } else if (EPI == 3){
          outH[(size_t)R*N + Cc] = (_Float16)(listw[R]*v);
        } else {
          int tk = list[R];
          float add = listw[R]*v;
          if (FUSED) atomicAdd(&outF[(size_t)tk*N + Cc], add);
          else outF[(size_t)tk*N + Cc] += add;
        }
      }
}

// ---------------- plain fp16 GEMM, 2-phase pipeline, BK=64 (for long-K: FFN2) ------
template<int EPI, int FUSED>
__global__ __launch_bounds__(256) void gemm_h64(
    const _Float16* __restrict__ A, const _Float16* __restrict__ A2, int Astride,
    const _Float16* __restrict__ Bw, _Float16* __restrict__ outH,
    float* __restrict__ outF, const int* __restrict__ list,
    const float* __restrict__ listw, const int* __restrict__ cntp,
    int M, int N, int K, int gmode, int cntMul, int Alim, int dmode,
    const int* __restrict__ offp)
{
  if (FUSED){
    int ez = blockIdx.y;
    cntp += ez;
    list += (ez<<13);
    if (listw) listw += (ez<<13);
    Bw += (size_t)ez * (size_t)N * (size_t)K;
    size_t so = (size_t)offp[ez];
    if (EPI == 1 || EPI == 3) outH += so * (size_t)N;
    if (EPI == 2 || EPI == 3) A += so * (size_t)Astride;
  }
  int Meff = M;
  if (cntp){ int cv = cntp[0]*cntMul; Meff = cv < M ? cv : M; }
  int nNB = N >> 7;
  int mb, nb;
  if (dmode == 2){
    int nMBa = (Meff + 127) >> 7;
    int T = nMBa * nNB;
    if ((int)blockIdx.x >= T) return;
    int swz = xcd_swz((int)blockIdx.x, T);
    mb = swz / nNB; nb = swz % nNB;
  } else {
    int bid = xcd_swz((int)blockIdx.x, (int)gridDim.x);
    decode_mb_nb(bid, nNB, M >> 7, dmode, mb, nb);
    if ((mb<<7) >= Meff) return;
  }
  __shared__ _Float16 lA[2][8192], lB[2][8192];
  int tid = threadIdx.x;
  int lane = tid & 63, wid = tid >> 6;
  int wr = wid >> 1, wc = wid & 1;
  int fr = lane & 15, fg = lane >> 4;
  f32x4 z = {0.f,0.f,0.f,0.f};
  f32x4 acc[4][4];
  #pragma unroll
  for (int m=0;m<4;m++)
    #pragma unroll
    for (int n=0;n<4;n++) acc[m][n] = z;

  size_t brow = (size_t)(nb<<7);
  int arow_s[4]; size_t boff_s[4]; int kcol_s[4];
  #pragma unroll
  for (int it=0; it<4; ++it){
    int q = (it<<8) + tid;
    int row = q >> 3, c8 = q & 7;
    int c8g = c8 ^ (row & 7);
    int gr = (mb<<7) + row;
    int grc = gr < (M-1) ? gr : (M-1);
    int sr2;
    if (gmode==0) sr2 = gr < (Meff-1) ? gr : (Meff-1);
    else if (gmode==1) sr2 = list[grc];
    else sr2 = (list[grc>>2]<<2) + (gr&3);
    sr2 = (sr2 < 0 || sr2 > Alim) ? 0 : sr2;
    arow_s[it] = sr2;
    kcol_s[it] = c8g<<3;
    boff_s[it] = (brow+row)*K + (c8g<<3);
  }

  auto STAGE = [&](int buf, int kt){
    #pragma unroll
    for (int it=0; it<4; ++it){
      int q = (it<<8) + tid;
      int kloc = kt + kcol_s[it];
      const _Float16* asrc;
      if (A2 != nullptr && kloc >= 1024) asrc = A2 + (size_t)arow_s[it]*Astride + (kloc-1024);
      else asrc = A + (size_t)arow_s[it]*Astride + kloc;
      gload16(asrc, &lA[buf][q<<3]);
      gload16(Bw + boff_s[it] + kt, &lB[buf][q<<3]);
    }
  };

  STAGE(0, 0);
  __syncthreads();
  int nk = K >> 6, cur = 0;
  for (int ki=0; ki<nk; ++ki){
    if (ki+1 < nk) STAGE(cur^1, (ki+1)<<6);
    #pragma unroll
    for (int kk2=0; kk2<2; ++kk2){
      int ko8 = (kk2<<2) + fg;
      half8 af[4], bf[4];
      #pragma unroll
      for (int m=0;m<4;m++){
        int r = (wr<<6)+(m<<4)+fr;
        af[m] = *(const half8*)&lA[cur][(r<<6) + ((ko8 ^ (r & 7))<<3)];
      }
      #pragma unroll
      for (int n=0;n<4;n++){
        int r = (wc<<6)+(n<<4)+fr;
        bf[n] = *(const half8*)&lB[cur][(r<<6) + ((ko8 ^ (r & 7))<<3)];
      }
      #pragma unroll
      for (int m=0;m<4;m++)
        #pragma unroll
        for (int n=0;n<4;n++)
          acc[m][n] = __builtin_amdgcn_mfma_f32_16x16x32_f16(af[m], bf[n], acc[m][n], 0,0,0);
    }
    __syncthreads();
    cur ^= 1;
  }
  int m0 = (mb<<7)+(wr<<6), n0 = (nb<<7)+(wc<<6);
  #pragma unroll
  for (int m=0;m<4;m++)
    #pragma unroll
    for (int n=0;n<4;n++)
      #pragma unroll
      for (int i=0;i<4;i++){
        int R = m0+(m<<4)+(fg<<2)+i;
        if (R >= Meff) continue;
        int Cc = n0+(n<<4)+fr;
        float v = acc[m][n][i];
        if (EPI == 0){
          outH[(size_t)R*N + Cc] = (_Float16)v;
        } else if (EPI == 1){
          v = v > 0.f ? v : 0.f;
          outH[(size_t)R*N + Cc] = (_Float16)(v*v);
        } else if (EPI == 3){
          outH[(size_t)R*N + Cc] = (_Float16)(listw[R]*v);
        } else {
          int tk = list[R];
          float add = listw[R]*v;
          if (FUSED) atomicAdd(&outF[(size_t)tk*N + Cc], add);
          else outF[(size_t)tk*N + Cc] += add;
        }
      }
}

// ---------------- FFN combine (no-atomic path): out0[t] += sum of staged rows ------
__global__ __launch_bounds__(256) void combine_ffn(
    const int* __restrict__ inv, const int* __restrict__ offp,
    const _Float16* __restrict__ stage, float* __restrict__ out0)
{
  int t = blockIdx.x, tid = threadIdx.x;
  float acc[4] = {0.f,0.f,0.f,0.f};
  #pragma unroll
  for (int s=0; s<2; ++s){
    int iv = inv[(t<<1)+s];
    int e = iv >> 13;
    if (e < 6){
      int p = iv & 8191;
      size_t row = (size_t)offp[e] + p;
      const _Float16* sp = stage + row*1024 + tid*4;
      #pragma unroll
      for (int j=0;j<4;j++) acc[j] += (float)sp[j];
    }
  }
  float* op = out0 + (size_t)t*1024 + tid*4;
  #pragma unroll
  for (int j=0;j<4;j++) op[j] += acc[j];
}

// ---------------- chunked RWKV scan: 3 passes (rkv fused input, stride 3072) -------
constexpr int SRD = 3072;

__global__ __launch_bounds__(64) void scan_passA(
    const float* __restrict__ rkv, const float* __restrict__ watt,
    float* __restrict__ states)
{
  const float* kb = rkv + 1024;
  const float* vb = rkv + 2048;
  int lane = threadIdx.x, bx = blockIdx.x;
  int chunk = bx & 15, bhq = bx >> 4;
  int b = bhq >> 6, h = (bhq >> 2) & 15, qq = bhq & 3;
  int dg = lane >> 4;
  int e = (qq<<4) + (lane & 15);
  float dec[16];
  #pragma unroll
  for (int i=0;i<16;i++){
    float wv = watt[(h<<6) + (dg<<4) + i];
    dec[i] = 1.f/(1.f + expf(-wv));
  }
  float st[16];
  #pragma unroll
  for (int i=0;i<16;i++) st[i]=0.f;
  __shared__ float sk[64];
  size_t rowbase = ((size_t)(b*1024 + chunk*64))*SRD + (h<<6);
  float pk[4], pv[4];
  #pragma unroll
  for (int j=0;j<4;j++){
    size_t o = rowbase + (size_t)j*SRD;
    pk[j]=kb[o+lane]; pv[j]=vb[o+e];
  }
  for (int t=0;t<64;t+=4){
    #pragma unroll
    for (int s4=0;s4<4;s4++){
      int tt = t+s4;
      sk[lane]=pk[s4];
      float ve = pv[s4];
      __syncthreads();
      if (tt+4 < 64){
        size_t o = rowbase + (size_t)(tt+4)*SRD;
        pk[s4]=kb[o+lane]; pv[s4]=vb[o+e];
      }
      const f32x4* K4 = (const f32x4*)&sk[dg<<4];
      #pragma unroll
      for (int j=0;j<4;j++){
        f32x4 kv = K4[j];
        #pragma unroll
        for (int ii=0;ii<4;ii++){
          int i=(j<<2)+ii;
          st[i] = st[i]*dec[i] + kv[ii]*ve;
        }
      }
      __syncthreads();
    }
  }
  float* sp = states + ((size_t)bhq*16 + chunk)*1024 + (lane<<4);
  #pragma unroll
  for (int i=0;i<16;i++) sp[i] = st[i];
}

__global__ __launch_bounds__(256) void scan_passB(
    float* __restrict__ states, const float* __restrict__ watt)
{
  int bhq = blockIdx.x;
  int h = (bhq >> 2) & 15;
  int t = threadIdx.x;
  int j0 = t*4;
  int d0 = ((j0>>8)<<4) + (j0&15);
  f32x4 wv = *(const f32x4*)(watt + (h<<6) + d0);
  f32x4 dec64;
  #pragma unroll
  for (int j=0;j<4;j++){
    float d = 1.f/(1.f + expf(-wv[j]));
    d = d*d; d = d*d; d = d*d; d = d*d; d = d*d; d = d*d;  // d^64
    dec64[j] = d;
  }
  f32x4 S = {0.f,0.f,0.f,0.f};
  float* base = states + (size_t)bhq*16*1024 + j0;
  for (int c=0;c<16;c++){
    f32x4 loc = *(f32x4*)(base + (size_t)c*1024);
    *(f32x4*)(base + (size_t)c*1024) = S;
    S = S*dec64 + loc;
  }
}

__global__ __launch_bounds__(64) void scan_passC(
    const float* __restrict__ rkv, const float* __restrict__ watt,
    const float* __restrict__ states,
    _Float16* __restrict__ outHi, _Float16* __restrict__ outLo)
{
  const float* rb = rkv;
  const float* kb = rkv + 1024;
  const float* vb = rkv + 2048;
  int lane = threadIdx.x, bx = blockIdx.x;
  int chunk = bx & 15, bhq = bx >> 4;
  int b = bhq >> 6, h = (bhq >> 2) & 15, qq = bhq & 3;
  int dg = lane >> 4;
  int e = (qq<<4) + (lane & 15);
  float dec[16];
  #pragma unroll
  for (int i=0;i<16;i++){
    float wv = watt[(h<<6) + (dg<<4) + i];
    dec[i] = 1.f/(1.f + expf(-wv));
  }
  float st[16];
  const float* sp = states + ((size_t)bhq*16 + chunk)*1024 + (lane<<4);
  #pragma unroll
  for (int i=0;i<16;i++) st[i] = sp[i];
  __shared__ float sk[64], sr[64];
  size_t rowbase = ((size_t)(b*1024 + chunk*64))*SRD + (h<<6);
  size_t obase   = ((size_t)(b*1024 + chunk*64))*1024 + (h<<6);
  float pk[4], pr[4], pv[4];
  #pragma unroll
  for (int j=0;j<4;j++){
    size_t o = rowbase + (size_t)j*SRD;
    pk[j]=kb[o+lane]; pr[j]=rb[o+lane]; pv[j]=vb[o+e];
  }
  for (int t=0;t<64;t+=4){
    #pragma unroll
    for (int s4=0;s4<4;s4++){
      int tt = t+s4;
      sk[lane]=pk[s4]; sr[lane]=pr[s4];
      float ve = pv[s4];
      __syncthreads();
      if (tt+4 < 64){
        size_t o = rowbase + (size_t)(tt+4)*SRD;
        pk[s4]=kb[o+lane]; pr[s4]=rb[o+lane]; pv[s4]=vb[o+e];
      }
      const f32x4* K4 = (const f32x4*)&sk[dg<<4];
      const f32x4* R4 = (const f32x4*)&sr[dg<<4];
      float p = 0.f;
      #pragma unroll
      for (int j=0;j<4;j++){
        f32x4 kv = K4[j], rv = R4[j];
        #pragma unroll
        for (int ii=0;ii<4;ii++){
          int i=(j<<2)+ii;
          st[i] = st[i]*dec[i] + kv[ii]*ve;
          p += rv[ii]*st[i];
        }
      }
      p += __shfl_xor(p, 16);
      p += __shfl_xor(p, 32);
      if (lane < 16){
        size_t o = obase + (size_t)tt*1024 + (qq<<4) + lane;
        float ps = p*16.f;
        _Float16 hi = (_Float16)ps;
        outHi[o] = hi;
        outLo[o] = (_Float16)(ps - (float)hi);
      }
      __syncthreads();
    }
  }
}

// ---------------- routing (64 tokens/block, block-aggregated atomics) ----------
// also records invPos[token*2+slot] = (expert<<13)|position for the combine pass.
__global__ __launch_bounds__(256) void routing_kernel(
    const float* __restrict__ hf, const float* __restrict__ Wcr,
    const float* __restrict__ Wct, const float* __restrict__ Wd,
    const float* __restrict__ Wa, const float* __restrict__ cap,
    int* __restrict__ cnt, int* __restrict__ listTok, float* __restrict__ listW,
    int* __restrict__ invPos)
{
  __shared__ int   lt[128];
  __shared__ int   le[128];
  __shared__ float lwv[128];
  int tid = threadIdx.x, wid = tid >> 6, lane = tid & 63;
  float cap8[8];
  #pragma unroll
  for (int e2=0;e2<8;e2++) cap8[e2] = cap[e2];

  for (int tt=0; tt<16; ++tt){
    int t = ((int)blockIdx.x<<6) + (wid<<4) + tt;
    const float* hrow = hf + (size_t)t*kC;
    float hr[16];
    #pragma unroll
    for (int i=0;i<16;i++) hr[i] = hrow[lane + (i<<6)];
    float dots[17];
    #pragma unroll
    for (int e2=0;e2<9;e2++){
      const float* wp = (e2<6) ? (Wcr + (size_t)e2*kC)
                    : (e2<8) ? (Wct + (size_t)(e2-6)*kC) : Wd;
      float a = 0.f;
      #pragma unroll
      for (int i=0;i<16;i++) a += hr[i]*wp[lane+(i<<6)];
      dots[e2] = a;
    }
    #pragma unroll
    for (int e2=0;e2<8;e2++){
      float a = 0.f;
      #pragma unroll
      for (int i=0;i<16;i++) a += hr[i]*Wa[(size_t)(lane+(i<<6))*8 + e2];
      dots[9+e2] = a;
    }
    #pragma unroll
    for (int e2=0;e2<17;e2++){
      float a = dots[e2];
      #pragma unroll
      for (int off=32; off; off>>=1) a += __shfl_xor(a, off);
      dots[e2] = a;
    }
    float diff = dots[8] > 20.f ? dots[8] : log1pf(expf(dots[8]));
    float am = dots[9];
    #pragma unroll
    for (int e2=1;e2<8;e2++) am = fmaxf(am, dots[9+e2]);
    float ee[8]; float es = 0.f;
    #pragma unroll
    for (int e2=0;e2<8;e2++){ ee[e2] = expf(dots[9+e2]-am); es += ee[e2]; }
    float inv = 1.f/es;
    float bids[8];
    #pragma unroll
    for (int e2=0;e2<8;e2++){
      float cf = 1.f/(1.f+expf(-dots[e2]));
      bids[e2] = cf*cap8[e2]*diff + ee[e2]*inv;
    }
    int i0=0; float v0=bids[0];
    #pragma unroll
    for (int e2=1;e2<8;e2++) if (bids[e2]>v0){ v0=bids[e2]; i0=e2; }
    int i1=-1; float v1=-1e30f;
    #pragma unroll
    for (int e2=0;e2<8;e2++) if (e2!=i0 && bids[e2]>v1){ v1=bids[e2]; i1=e2; }
    float x1 = expf(v1-v0);
    float w0 = 1.f/(1.f+x1);
    float w1 = x1/(1.f+x1);
    if (lane==0){
      int slot = (((wid<<4)+tt)<<1);
      lt[slot]   = t; le[slot]   = i0; lwv[slot]   = w0;
      lt[slot+1] = t; le[slot+1] = i1; lwv[slot+1] = w1;
    }
  }
  __syncthreads();
  if (tid < 8){
    int c = 0;
    for (int j=0;j<128;j++) c += (le[j]==tid) ? 1 : 0;
    int b = atomicAdd(&cnt[tid], c);
    for (int j=0;j<128;j++){
      if (le[j]==tid){
        listTok[(tid<<13)+b] = lt[j];
        listW[(tid<<13)+b]  = lwv[j];
        invPos[(lt[j]<<1) + (j&1)] = (tid<<13) + b;
        ++b;
      }
    }
  }
}

// ---------------- transformer-expert attention (P=4 prefix) ----------------
__global__ __launch_bounds__(256) void attn_logits(
    const _Float16* __restrict__ q, const _Float16* __restrict__ kp,
    float* __restrict__ attw, const int* __restrict__ cntp)
{
  int cnt = cntp[0];
  int gw = ((int)blockIdx.x<<2) + (threadIdx.x>>6);
  int r = gw >> 4, h = gw & 15;
  if (r >= cnt) return;
  int lane = threadIdx.x & 63;
  float qd = (float)q[(size_t)r*kC + (h<<6) + lane];
  float lg[4];
  #pragma unroll
  for (int p=0;p<4;p++){
    float kd = (float)kp[((size_t)(r<<2)+p)*kC + (h<<6) + lane];
    float a = qd*kd;
    #pragma unroll
    for (int off=32; off; off>>=1) a += __shfl_xor(a, off);
    lg[p] = a*0.125f;
  }
  float mx = fmaxf(fmaxf(lg[0],lg[1]),fmaxf(lg[2],lg[3]));
  float ex[4]; float s = 0.f;
  #pragma unroll
  for (int p=0;p<4;p++){ ex[p] = expf(lg[p]-mx); s += ex[p]; }
  float inv = 1.f/s;
  if (lane < 4){
    float pv_ = (lane==0) ? ex[0] : (lane==1) ? ex[1] : (lane==2) ? ex[2] : ex[3];
    attw[((size_t)r<<6) + (h<<2) + lane] = pv_*inv;
  }
}

__global__ __launch_bounds__(256) void attn_av(
    const float* __restrict__ attw, const _Float16* __restrict__ vp,
    _Float16* __restrict__ o, const int* __restrict__ cntp)
{
  int cnt = cntp[0];
  int idx = (int)blockIdx.x*256 + threadIdx.x;
  int r = idx >> 10;
  if (r >= cnt) return;
  int c = idx & 1023; int h = c >> 6;
  const float* aw = attw + ((size_t)r<<6) + (h<<2);
  float s = 0.f;
  #pragma unroll
  for (int p=0;p<4;p++) s += aw[p] * (float)vp[((size_t)(r<<2)+p)*kC + c];
  o[(size_t)r*kC + c] = (_Float16)s;
}

// ---------------- launch ----------------
extern "C" void kernel_launch(void* const* d_in, const int* in_sizes, int n_in,
                              void* d_out, int out_size, void* d_ws, size_t ws_size,
                              hipStream_t stream) {
  if (ws_size < WS_NEED) return;
  const bool bigws = (ws_size >= WS_BIG);
  const float* x    = (const float*)d_in[0];
  const float* cap  = (const float*)d_in[2];
  const float* g1   = (const float*)d_in[3];
  const float* b1   = (const float*)d_in[4];
  const float* g2   = (const float*)d_in[5];
  const float* b2   = (const float*)d_in[6];
  const float* Wr   = (const float*)d_in[7];
  const float* Wk   = (const float*)d_in[8];
  const float* Wv   = (const float*)d_in[9];
  const float* Wo   = (const float*)d_in[10];
  const float* watt = (const float*)d_in[11];
  const float* Wb   = (const float*)d_in[12];
  const float* Wkf  = (const float*)d_in[13];
  const float* Wvf  = (const float*)d_in[14];
  const float* Wcr  = (const float*)d_in[15];
  const float* Wqt  = (const float*)d_in[16];
  const float* Wkt  = (const float*)d_in[17];
  const float* Wvt  = (const float*)d_in[18];
  const float* Wot  = (const float*)d_in[19];
  const float* Wct  = (const float*)d_in[20];
  const float* Wd   = (const float*)d_in[21];
  const float* Wa   = (const float*)d_in[22];

  float* out0 = (float*)d_out;
  float* vout = out0 + CB;
  char* w = (char*)d_ws;
  _Float16* W1h  = (_Float16*)(w+O_W1H);
  _Float16* W1l  = (_Float16*)(w+O_W1L);
  _Float16* WoTh = (_Float16*)(w+O_WOH); _Float16* WoTl = (_Float16*)(w+O_WOL);
  _Float16* WbT  = (_Float16*)(w+O_WBT);
  _Float16* WkfT = (_Float16*)(w+O_WKF);
  _Float16* WvfT = (_Float16*)(w+O_WVF);
  _Float16* WqtT = (_Float16*)(w+O_WQT);
  _Float16* WktT = (_Float16*)(w+O_WKT);
  _Float16* WvtT = (_Float16*)(w+O_WVT);
  _Float16* WotT = (_Float16*)(w+O_WOT);
  _Float16* xlnHi= (_Float16*)(w+O_XH);
  _Float16* xlnLo= (_Float16*)(w+O_XL);
  float*    rkv  = (float*)(w+O_RKV);
  float*    stbuf= (float*)(w+O_XH);
  _Float16* rwHi = (_Float16*)(w+O_RWH);
  _Float16* rwLo = (_Float16*)(w+O_RWL);
  float*    hF   = (float*)(w+O_RKV);
  _Float16* hH   = (_Float16*)(w+O_RWL);
  _Float16* kkpool = (_Float16*)(w+O_XH);       // [144,272) during FFN
  _Float16* pfxE = (_Float16*)(w+O_XH);         // per-expert prefix [144,208)
  _Float16* kvE  = (_Float16*)(w+O_RKV+32*MB1); // kp/vp time-share [208,272)
  _Float16* pfxD = (_Float16*)(w+O_RKV+32*MB1); // dense prefix (fallback) [208,272)
  _Float16* kpF  = (_Float16*)(w+O_XH);         // fallback kp/vp [144,208)
  float*    attw = (float*)(w+O_AW);
  int*      cnt  = (int*)(w+O_CNT);
  int*      offp = (int*)(w+O_OFF);
  int*   listTok = (int*)(w+O_LTOK);
  float* listW   = (float*)(w+O_LW);
  int*   invPos  = (int*)(w+O_INV);
  _Float16* stageH = (_Float16*)(w+O_STAGE);
  // bigws: q/o live in the stage region (dead after combine) so rwHi survives
  _Float16* qH = bigws ? stageH            : (_Float16*)(w+O_RWH);
  _Float16* oH = bigws ? stageH + 8388608  : (_Float16*)(w+O_RWH);

  dim3 TB(256);
  zero_cnt<<<1,64,0,stream>>>(cnt);

  // weight transposes (+x64 hi/lo split for stage-1; QKV stacked [3072][1024])
  transpose_cvt<<<dim3(32,32,1),TB,0,stream>>>(Wr, W1h,           W1l,           1024,1024, 64.f,64.f,1024, 1);
  transpose_cvt<<<dim3(32,32,1),TB,0,stream>>>(Wk, W1h+1024*1024, W1l+1024*1024, 1024,1024, 64.f,64.f,1024, 1);
  transpose_cvt<<<dim3(32,32,1),TB,0,stream>>>(Wv, W1h+2048*1024, W1l+2048*1024, 1024,1024, 64.f,64.f,1024, 1);
  transpose_cvt<<<dim3(32,32,1),TB,0,stream>>>(Wo, WoTh, WoTl, 1024,1024, 64.f,64.f,1024, 1);
  transpose_cvt<<<dim3(128,64,1),TB,0,stream>>>(Wb,  WbT,  nullptr, 2048,4096, 1.f, 1.f/16.f, 1024, 0);
  transpose_cvt<<<dim3(128,32,6),TB,0,stream>>>(Wkf, WkfT, nullptr, 1024,4096, 1.f,1.f,9999, 0);
  transpose_cvt<<<dim3(32,128,6),TB,0,stream>>>(Wvf, WvfT, nullptr, 4096,1024, 1.f,1.f,9999, 0);
  transpose_cvt<<<dim3(32,32,2),TB,0,stream>>>(Wqt, WqtT, nullptr, 1024,1024, 1.f,1.f,9999, 0);
  transpose_cvt<<<dim3(32,32,2),TB,0,stream>>>(Wkt, WktT, nullptr, 1024,1024, 1.f,1.f,9999, 0);
  transpose_cvt<<<dim3(32,32,2),TB,0,stream>>>(Wvt, WvtT, nullptr, 1024,1024, 1.f,1.f,9999, 0);
  transpose_cvt<<<dim3(32,32,2),TB,0,stream>>>(Wot, WotT, nullptr, 1024,1024, 1.f,1.f,9999, 0);

  // stage 1: fused r|k|v emulated GEMM (N=3072), v-columns also -> v_first output
  ln_kernel<<<8192,TB,0,stream>>>(x, g1, b1, nullptr, nullptr, xlnHi, xlnLo, 16.f);
  gemm_emu<0><<<1536,TB,0,stream>>>(xlnHi, xlnLo, W1h, W1l, rkv, nullptr, vout,
                                    8192, 3072, 1024);
  scan_passA<<<8192,64,0,stream>>>(rkv, watt, stbuf);
  scan_passB<<<512,256,0,stream>>>(stbuf, watt);
  scan_passC<<<8192,64,0,stream>>>(rkv, watt, stbuf, rwHi, rwLo);
  gemm_emu<1><<<512,TB,0,stream>>>(rwHi, rwLo, WoTh, WoTl, out0, x, nullptr,
                                   8192, 1024, 1024);
  ln_kernel<<<8192,TB,0,stream>>>(out0, g2, b2, hF, hH, nullptr, nullptr, 1.f);

  // routing (block-aggregated atomics; records inverse map) + kk segment offsets
  routing_kernel<<<128,TB,0,stream>>>(hF, Wcr, Wct, Wd, Wa, cap, cnt, listTok, listW, invPos);
  calc_off<<<1,64,0,stream>>>(cnt, offp);

  // 6 SparseRWKVFFN experts, fused across experts, dmode=2.
  // FFN1 (K=1024): BK=32 variant. FFN2 (K=4096): BK=64 variant (fewer barriers).
  gemm_h<1,1><<<dim3(2048,6),TB,0,stream>>>(hH, nullptr, 1024, WkfT, kkpool,
                                  nullptr, listTok, nullptr, cnt,
                                  8192, 4096, 1024, 1, 1, 8191, 2, offp);
  if (bigws){
    gemm_h64<3,1><<<dim3(512,6),TB,0,stream>>>(kkpool, nullptr, 4096, WvfT, stageH,
                                    nullptr, listTok, listW, cnt,
                                    8192, 1024, 4096, 0, 1, 8191, 2, offp);
    combine_ffn<<<8192,TB,0,stream>>>(invPos, offp, stageH, out0);
  } else {
    gemm_h64<2,1><<<dim3(512,6),TB,0,stream>>>(kkpool, nullptr, 4096, WvfT, nullptr,
                                    out0, listTok, listW, cnt,
                                    8192, 1024, 4096, 0, 1, 8191, 2, offp);
  }

  if (bigws){
    // per-expert gathered prefix; q/o in stage region (rwHi stays intact)
    for (int e = 0; e < 2; ++e){
      int ge = 6 + e;
      gemm_h<0,0><<<64*32,TB,0,stream>>>(hH, rwHi, 1024, WbT, pfxE, nullptr,
                                      listTok+ge*8192, nullptr, cnt+ge,
                                      8192, 4096, 2048, 1, 1, 8191, 2, nullptr);
      gemm_h<0,0><<<64*8,TB,0,stream>>>(hH, nullptr, 1024, WqtT + (size_t)e*kC*kC, qH,
                                      nullptr, listTok+ge*8192, nullptr, cnt+ge,
                                      8192, 1024, 1024, 1, 1, 8191, 2, nullptr);
      gemm_h<0,0><<<256*8,TB,0,stream>>>(pfxE, nullptr, 1024, WktT + (size_t)e*kC*kC, kvE,
                                       nullptr, listTok+ge*8192, nullptr, cnt+ge,
                                       32768, 1024, 1024, 0, 4, 32767, 2, nullptr);
      attn_logits<<<32768,TB,0,stream>>>(qH, kvE, attw, cnt+ge);
      gemm_h<0,0><<<256*8,TB,0,stream>>>(pfxE, nullptr, 1024, WvtT + (size_t)e*kC*kC, kvE,
                                       nullptr, listTok+ge*8192, nullptr, cnt+ge,
                                       32768, 1024, 1024, 0, 4, 32767, 2, nullptr);
      attn_av<<<32768,TB,0,stream>>>(attw, kvE, oH, cnt+ge);
      gemm_h<2,0><<<64*8,TB,0,stream>>>(oH, nullptr, 1024, WotT + (size_t)e*kC*kC, nullptr,
                                      out0, listTok+ge*8192, listW+ge*8192, cnt+ge,
                                      8192, 1024, 1024, 0, 1, 8191, 2, nullptr);
    }
  } else {
    // fallback (round-13/14 semantics): dense prefix once, then gathered kp/vp.
    gemm_h<0,0><<<64*32,TB,0,stream>>>(hH, rwHi, 1024, WbT, pfxD, nullptr,
                                     nullptr, nullptr, nullptr, 8192, 4096, 2048, 0, 1, 8191, 0, nullptr);
    for (int e = 0; e < 2; ++e){
      int ge = 6 + e;
      gemm_h<0,0><<<64*8,TB,0,stream>>>(hH, nullptr, 1024, WqtT + (size_t)e*kC*kC, qH,
                                      nullptr, listTok+ge*8192, nullptr, cnt+ge,
                                      8192, 1024, 1024, 1, 1, 8191, 2, nullptr);
      gemm_h<0,0><<<256*8,TB,0,stream>>>(pfxD, nullptr, 1024, WktT + (size_t)e*kC*kC, kpF,
                                       nullptr, listTok+ge*8192, nullptr, cnt+ge,
                                       32768, 1024, 1024, 2, 4, 32767, 2, nullptr);
      attn_logits<<<32768,TB,0,stream>>>(qH, kpF, attw, cnt+ge);
      gemm_h<0,0><<<256*8,TB,0,stream>>>(pfxD, nullptr, 1024, WvtT + (size_t)e*kC*kC, kpF,
                                       nullptr, listTok+ge*8192, nullptr, cnt+ge,
                                       32768, 1024, 1024, 2, 4, 32767, 2, nullptr);
      attn_av<<<32768,TB,0,stream>>>(attw, kpF, oH, cnt+ge);
      gemm_h<2,0><<<64*8,TB,0,stream>>>(oH, nullptr, 1024, WotT + (size_t)e*kC*kC, nullptr,
                                      out0, listTok+ge*8192, listW+ge*8192, cnt+ge,
                                      8192, 1024, 1024, 0, 1, 8191, 2, nullptr);
    }
  }
}